// Round 11
// baseline (788.777 us; speedup 1.0000x reference)
//
#include <hip/hip_runtime.h>
#include <math.h>

#define D    128
#define QN   4
#define CN   4
#define MAXC 4
#define BB   128
#define SS   64
#define RK   10
#define T    768   // 12 waves

// ---- packed-fp16 weight workspace layout (uint32 units; each uint = 2 half) ----
#define UOFF_IH1A 0        // cols 0..127 of W_ih1, chunked NT=768 K=8 (streamed) -> 24576
#define UOFF_IH1B 24576    // cols 128..255 of W_ih1: [e2l][384] -> 24576
#define UOFF_HH1  49152    // chunked NT=768 K=8 (streamed, overlapped in P3/P4) -> 24576
#define UOFF_IH2  73728    // chunked NT=768 K=8 (register-pinned, 64 regs w/ HH2) -> 24576
#define UOFF_HH2  98304    // chunked NT=768 K=8 (register-pinned) -> 24576
#define UOFF_QRY  122880   // [k][128] uint4, K=16 -> 8192
#define UOFF_A0   131072   // [e2g][2][128] -> 8192
#define UOFF_A1   139264   // -> 8192
#define UOFF_LS   147456   // -> 8192
#define TOTAL_U   155648

typedef _Float16 h2_t __attribute__((ext_vector_type(2)));
union U32H2 { unsigned u; h2_t h; unsigned short s2[2]; };

__device__ __forceinline__ unsigned h16f(float x){
  U32H2 c; c.h[0] = (_Float16)x; c.h[1] = (_Float16)0.f;
  return (unsigned)c.s2[0];
}
__device__ __forceinline__ unsigned packh2(float a, float b){
  U32H2 c; c.h[0] = (_Float16)a; c.h[1] = (_Float16)b;
  return c.u;
}
__device__ __forceinline__ float dot2(unsigned w, unsigned x, float acc){
  U32H2 a; a.u = w; U32H2 b; b.u = x;
  return __builtin_amdgcn_fdot2(a.h, b.h, acc, false);
}
__device__ __forceinline__ float hlo(unsigned u){ U32H2 a; a.u=u; return (float)a.h[0]; }
__device__ __forceinline__ float hhi(unsigned u){ U32H2 a; a.u=u; return (float)a.h[1]; }

__device__ __forceinline__ float fsig(float x){ return 1.f/(1.f + __expf(-x)); }
__device__ __forceinline__ float ftanh(float x){
  float xc = fminf(fmaxf(x, -30.f), 30.f);
  float e = __expf(2.f*xc);
  return (e - 1.f)/(e + 1.f);
}

#define FD4(w4, x4, acc) { \
  acc = dot2((w4).x, (x4).x, acc); acc = dot2((w4).y, (x4).y, acc); \
  acc = dot2((w4).z, (x4).z, acc); acc = dot2((w4).w, (x4).w, acc); }

// anti-rematerialization pin. HARD LIMIT: 64 pinned regs total — the allocator
// caps at ~84 VGPRs (r8/r9/r10: every larger pin set spilled to scratch).
#define KEEP4(v) asm volatile("" : "+v"((v).x), "+v"((v).y), "+v"((v).z), "+v"((v).w))

__global__ void gikt_pack(const float* __restrict__ Wih1,
                          const float* __restrict__ Whh1,
                          const float* __restrict__ Wih2,
                          const float* __restrict__ Whh2,
                          const float* __restrict__ Wagg,
                          const float* __restrict__ Wlast,
                          const float* __restrict__ Wqry,
                          unsigned* __restrict__ wsU)
{
  int i = blockIdx.x * blockDim.x + threadIdx.x;
  if (i >= TOTAL_U) return;
  const float* src = nullptr; int row = 0, e2 = 0, stride = 0;
  int j = i;
  if (j < 24576) {               // ih1a
    int c = j & 3, i4 = j >> 2, k = i4 / 768, t = i4 - k * 768, r = t >> 1, hf = t & 1;
    e2 = hf * 32 + k * 4 + c; row = r; src = Wih1; stride = 256;
  } else if ((j -= 24576) < 24576) {   // ih1b
    e2 = 64 + (j / 384); row = j % 384; src = Wih1; stride = 256;
  } else if ((j -= 24576) < 24576) {   // hh1
    int c = j & 3, i4 = j >> 2, k = i4 / 768, t = i4 - k * 768, r = t >> 1, hf = t & 1;
    e2 = hf * 32 + k * 4 + c; row = r; src = Whh1; stride = 128;
  } else if ((j -= 24576) < 24576) {   // ih2
    int c = j & 3, i4 = j >> 2, k = i4 / 768, t = i4 - k * 768, r = t >> 1, hf = t & 1;
    e2 = hf * 32 + k * 4 + c; row = r; src = Wih2; stride = 128;
  } else if ((j -= 24576) < 24576) {   // hh2
    int c = j & 3, i4 = j >> 2, k = i4 / 768, t = i4 - k * 768, r = t >> 1, hf = t & 1;
    e2 = hf * 32 + k * 4 + c; row = r; src = Whh2; stride = 128;
  } else if ((j -= 24576) < 8192) {    // qry
    int c = j & 3, i4 = j >> 2, k = i4 >> 7, r = i4 & 127;
    e2 = k * 4 + c; row = r; src = Wqry; stride = 128;
  } else if ((j -= 8192) < 8192) {     // a0
    int r = j & 127, p = (j >> 7) & 1, e2g = j >> 8;
    e2 = 2 * e2g + p; row = r; src = Wagg; stride = 128;
  } else if ((j -= 8192) < 8192) {     // a1
    int r = j & 127, p = (j >> 7) & 1, e2g = j >> 8;
    e2 = 2 * e2g + p; row = r; src = Wagg + 128 * 128; stride = 128;
  } else {                              // ls
    j -= 8192;
    int r = j & 127, p = (j >> 7) & 1, e2g = j >> 8;
    e2 = 2 * e2g + p; row = r; src = Wlast; stride = 128;
  }
  float lo = src[row * stride + 2 * e2];
  float hi = src[row * stride + 2 * e2 + 1];
  wsU[i] = h16f(lo) | (h16f(hi) << 16);
}

__device__ __forceinline__ float2 gru_nl2(float2 gr, float2 gz, float2 gn,
                                          float2 hr, float2 hz, float2 hn,
                                          float2 hold){
  float2 out;
  {
    float rg = fsig(gr.x + hr.x);
    float zg = fsig(gz.x + hz.x);
    float ng = ftanh(gn.x + rg*hn.x);
    out.x = (1.f-zg)*ng + zg*hold.x;
  }
  {
    float rg = fsig(gr.y + hr.y);
    float zg = fsig(gz.y + hz.y);
    float ng = ftanh(gn.y + rg*hn.y);
    out.y = (1.f-zg)*ng + zg*hold.y;
  }
  return out;
}

__launch_bounds__(T, 1)
__global__ void gikt_main(
    const float* __restrict__ embQ,
    const float* __restrict__ embC,
    const float* __restrict__ embR,
    const float* __restrict__ b_ih1,
    const float* __restrict__ b_hh1,
    const float* __restrict__ b_ih2,
    const float* __restrict__ b_hh2,
    const float* __restrict__ b_agg,
    const float* __restrict__ b_last,
    const float* __restrict__ b_query,
    const float* __restrict__ w_k,
    const float* __restrict__ h1i,
    const float* __restrict__ h2i,
    const int* __restrict__ qnbr,
    const int* __restrict__ cnbr,
    const int* __restrict__ q2c,
    const int* __restrict__ qseq,
    const int* __restrict__ cseq,
    const int* __restrict__ mseq,
    const unsigned* __restrict__ wsU,
    float* __restrict__ y)
{
  const int b   = blockIdx.x;
  const int tid = threadIdx.x;
  const int r2  = tid >> 1, hf = tid & 1;

  __shared__ unsigned aggL[3 * 8192];          // a0|a1|ls; phase0 alias: Gram
  __shared__ __align__(16) float hist[SS][132];// state history fp32 (row0 = zero)
  __shared__ float gicorr[2][384];
  __shared__ int   idxk[SS][RK];
  __shared__ float kwh[SS];
  __shared__ __align__(16) float a_[5][D];
  __shared__ __align__(16) float gi1[3*D];
  __shared__ __align__(16) float gh1[3*D];
  __shared__ __align__(16) float gi2[3*D];
  __shared__ __align__(16) float gh2[3*D];
  __shared__ __align__(16) float h1fp[2][D];
  __shared__ __align__(16) float g2fp[2][D];
  __shared__ __align__(16) float h2ifp[D];
  __shared__ __align__(16) float qcs[2][D];
  __shared__ float kevec[D];
  __shared__ __align__(16) unsigned mPu[5][64];
  __shared__ __align__(16) unsigned vPu[64];
  __shared__ __align__(16) unsigned m1Pu[64];
  __shared__ __align__(16) unsigned xvPu[64];
  __shared__ __align__(16) unsigned h1Pu[64];
  __shared__ __align__(16) unsigned g2Pu[64];
  __shared__ __align__(16) unsigned h2iPu[64];
  __shared__ int   sq[SS], scc[SS], smk[SS];
  __shared__ int   nn1[SS][QN], nn2[SS][QN*CN], cc2[SS][MAXC];
  __shared__ float red[12];
  __shared__ float ogv[16], kwv[16];

  float (*G)[65] = (float(*)[65])aggL;

  // ---- pinned GRU2 weights: 16 uint4 = 64 VGPR (proven-safe envelope) ----
  uint4 pwi[8], pwh[8];
  {
    const uint4* Pi = (const uint4*)(wsU + UOFF_IH2);
    const uint4* Ph = (const uint4*)(wsU + UOFF_HH2);
    #pragma unroll
    for (int k = 0; k < 8; ++k) { pwi[k] = Pi[k*768 + tid]; pwh[k] = Ph[k*768 + tid]; }
    #pragma unroll
    for (int k = 0; k < 8; ++k) { KEEP4(pwi[k]); KEEP4(pwh[k]); }
  }

  // ---- phase 0a: sequences ----
  for (int i = tid; i < SS; i += T) { sq[i]=qseq[b*SS+i]; scc[i]=cseq[b*SS+i]; smk[i]=mseq[b*SS+i]; }
  __syncthreads();

  // ---- phase 0b: E rows into hist; 1-hop indices ----
  for (int i = tid; i < SS*32; i += T) {
    int s = i >> 5, e4 = i & 31;
    float4 v = ((const float4*)(embQ + sq[s]*D))[e4];
    ((float4*)hist[s])[e4] = v;
  }
  for (int i = tid; i < (SS-1)*QN; i += T)   { int t = i>>2, j = i&3; nn1[t][j] = qnbr[sq[t]*QN + j]; }
  for (int i = tid; i < (SS-1)*MAXC; i += T) { int t = i>>2, j = i&3; cc2[t][j] = q2c[sq[t+1]*MAXC + j]; }
  __syncthreads();

  // ---- phase 0c: Gram (fp32, float4), 2-hop indices, gicorr ----
  for (int p = tid; p < SS*SS; p += T) {
    int tq = p >> 6, s = p & 63;
    if (tq >= RK+2 && s < tq-1) {
      const float4* ra = (const float4*)hist[tq];
      const float4* rb = (const float4*)hist[s];
      float acc = 0.f;
      #pragma unroll 8
      for (int d4 = 0; d4 < 32; ++d4) {
        float4 xa = ra[d4], xb = rb[d4];
        acc += xa.x*xb.x + xa.y*xb.y + xa.z*xb.z + xa.w*xb.w;
      }
      G[tq-(RK+2)][s] = acc;
    }
  }
  for (int i = tid; i < (SS-1)*QN*CN; i += T) {
    int t = i>>4, j = (i>>2)&3, l = i&3;
    nn2[t][j*CN+l] = cnbr[nn1[t][j]*CN + l];
  }
  {
    const int c = (tid >= 384) ? 1 : 0, r = tid - (c ? 384 : 0);
    const float2* er2 = (const float2*)(embR + c*D);
    float acc = 0.f;
    #pragma unroll 4
    for (int e2l = 0; e2l < 64; ++e2l) {
      unsigned u = wsU[UOFF_IH1B + e2l*384 + r];
      float2 x = er2[e2l];
      acc += hlo(u)*x.x + hhi(u)*x.y;
    }
    gicorr[c][r] = acc;
  }
  __syncthreads();

  // ---- phase 0d: stable top-k (ties -> lowest index, = jax.lax.top_k) ----
  if (tid < 52) {
    int t = RK + 1 + tid;
    for (int k = 0; k < RK; ++k) {
      float best = -INFINITY; int bi = 0;
      for (int s = 0; s < t; ++s) { float v = G[tid][s]; if (v > best) { best = v; bi = s; } }
      idxk[t][k] = bi;
      G[tid][bi] = -INFINITY;
    }
  }
  __syncthreads();

  // ---- phase 0e: agg weights into LDS; state init; kw(zero-state) ----
  for (int i = tid; i < 3*8192; i += T) aggL[i] = wsU[UOFF_A0 + i];
  if (tid < 64) {
    float a0 = h1i[b*D+2*tid], a1 = h1i[b*D+2*tid+1];
    h1Pu[tid] = packh2(a0, a1);
    ((float2*)h1fp[1])[tid] = make_float2(a0, a1);
    float c0 = h2i[b*D+2*tid], c1 = h2i[b*D+2*tid+1];
    h2iPu[tid] = packh2(c0, c1);
    ((float2*)h2ifp)[tid] = make_float2(c0, c1);
    g2Pu[tid] = 0;
  }
  if (tid < D) hist[0][tid] = 0.f;
  if (tid == 0) y[b*SS + 1] = 0.f;   // never written by reference
  {
    float p0 = (tid < D) ? w_k[tid]*ftanh(b_query[tid]) : 0.f;
    #pragma unroll
    for (int off = 32; off; off >>= 1) p0 += __shfl_down(p0, off);
    if ((tid & 63) == 0) red[tid >> 6] = p0;
  }
  __syncthreads();
  if (tid == 0) kwh[0] = red[0]+red[1];
  __syncthreads();

  const uint4* Wi1 = (const uint4*)(wsU + UOFF_IH1A);
  const uint4* Wh1 = (const uint4*)(wsU + UOFF_HH1);
  const uint4* Wq4 = (const uint4*)(wsU + UOFF_QRY);

  // 1-thread/row hh1 matvec (gh1[r]); overlapped into P3/P4 idle lanes
#define GH1_ROW(r) {                                                   \
    const uint4* h1p4_ = (const uint4*)h1Pu;                           \
    float a0_ = b_hh1[r], a1_ = 0.f;                                   \
    _Pragma("unroll")                                                  \
    for (int k = 0; k < 8; ++k) {                                      \
      uint4 u0_ = Wh1[k*768 + 2*(r)], u1_ = Wh1[k*768 + 2*(r) + 1];    \
      FD4(u0_, h1p4_[k], a0_); FD4(u1_, h1p4_[8+k], a1_);              \
    }                                                                  \
    gh1[r] = a0_ + a1_; }

  // ---- cross-step gather prefetch registers ----
  float pf0 = 0.f, pf1 = 0.f, pf2 = 0.f, pf3 = 0.f, pf4 = 0.f;

#define PREFETCH(tt) {                                                        \
    const int d_ = tid & 127, grp_ = tid >> 7;                                \
    const bool m2_ = (smk[tt] != 0);                                          \
    if (grp_ == 0) {                                                          \
      pf0 = embQ[sq[tt]*D + d_];                                              \
      if (m2_) { pf1 = embC[nn1[tt][0]*D+d_]; pf2 = embC[nn1[tt][1]*D+d_];    \
                 pf3 = embC[nn1[tt][2]*D+d_]; pf4 = embC[nn1[tt][3]*D+d_]; }  \
    } else if (grp_ <= 4) {                                                   \
      if (m2_) { const int j_ = grp_ - 1;                                     \
        pf0 = embC[nn1[tt][j_]*D + d_];                                       \
        pf1 = embQ[nn2[tt][j_*CN+0]*D+d_]; pf2 = embQ[nn2[tt][j_*CN+1]*D+d_]; \
        pf3 = embQ[nn2[tt][j_*CN+2]*D+d_]; pf4 = embQ[nn2[tt][j_*CN+3]*D+d_];}\
    } else {                                                                  \
      pf0 = embQ[sq[(tt)+1]*D + d_];                                          \
      pf1 = embC[cc2[tt][0]*D+d_]; pf2 = embC[cc2[tt][1]*D+d_];               \
      pf3 = embC[cc2[tt][2]*D+d_]; pf4 = embC[cc2[tt][3]*D+d_];               \
    } }

  PREFETCH(0);

  // ==== time loop ====
  for (int t = 0; t < SS-1; ++t) {
    const int tp = t - 1;
    const bool msk = (smk[t] != 0);

    // ---- P1: wave0 finalizes g2(t-1); consume prefetch; issue prefetch(t+1) ----
    if (tid < 64 && t >= 1) {
      const int l = tid;
      const float* ph2 = (t <= 2) ? h2ifp : g2fp[t & 1];
      float2 hold = ((const float2*)ph2)[l];
      float2 gv = gru_nl2(((const float2*)gi2)[l], ((const float2*)(gi2+128))[l], ((const float2*)(gi2+256))[l],
                          ((const float2*)gh2)[l], ((const float2*)(gh2+128))[l], ((const float2*)(gh2+256))[l],
                          hold);
      ((float2*)g2fp[(t+1)&1])[l] = gv;
      g2Pu[l] = packh2(gv.x, gv.y);
      if (t >= 2) { hist[t-1][2*l] = gv.x; hist[t-1][2*l+1] = gv.y; }
    }
    {
      const int d = tid & 127, grp = tid >> 7;
      if (msk) {
        if (grp <= 4) ((_Float16*)mPu[grp])[d] = (_Float16)(pf0 + 0.25f*(pf1+pf2+pf3+pf4));
        else          qcs[t & 1][d] = pf0+pf1+pf2+pf3+pf4;
      } else {
        if (grp == 0)      ((_Float16*)xvPu)[d] = (_Float16)pf0;
        else if (grp == 5) qcs[t & 1][d] = pf0+pf1+pf2+pf3+pf4;
      }
    }
    if (t + 1 < SS-1) PREFETCH(t+1);
    __syncthreads();

    if (msk) {
      // ---- P2: agg1 1thr/row (0-639) | qry 1thr/row (640-767) ----
      if (tid < 640) {
        const int which = tid >> 7, r = tid & 127;
        const unsigned* A = aggL + (which ? 8192 : 0);
        const uint2* x2p = (const uint2*)mPu[which];
        float acc0 = (which == 0) ? b_agg[r] : b_agg[D + r], acc1 = 0.f;
        #pragma unroll
        for (int e2g = 0; e2g < 32; e2g += 2) {
          unsigned u00 = A[e2g*256 + r],     u01 = A[e2g*256 + 128 + r];
          uint2 x0 = x2p[e2g];
          acc0 = dot2(u00, x0.x, acc0); acc0 = dot2(u01, x0.y, acc0);
          unsigned u10 = A[(e2g+1)*256 + r], u11 = A[(e2g+1)*256 + 128 + r];
          uint2 x1 = x2p[e2g+1];
          acc1 = dot2(u10, x1.x, acc1); acc1 = dot2(u11, x1.y, acc1);
        }
        a_[which][r] = ftanh(acc0 + acc1);
      } else {
        const int r = tid - 640;
        const uint4* g2p4 = (const uint4*)g2Pu;
        float a0 = b_query[r], a1 = 0.f;
        #pragma unroll
        for (int k = 0; k < 16; k += 2) {
          uint4 u0 = Wq4[k*128 + r];     uint4 x0 = g2p4[k];   FD4(u0, x0, a0);
          uint4 u1 = Wq4[(k+1)*128 + r]; uint4 x1 = g2p4[k+1]; FD4(u1, x1, a1);
        }
        kevec[r] = ftanh(a0 + a1) * w_k[r];
      }
      __syncthreads();

      // ---- P3: agg2 (0-255) | og (256-431) | gh1 rows 0-79 (432-511) |
      //          kw-reduce (512-575) | gh1 rows 80-271 (576-767) ----
      if (tid < 256) {
        const int l = tid & 63;
        float v0 = a_[0][2*l]   + 0.25f*(a_[1][2*l]  +a_[2][2*l]  +a_[3][2*l]  +a_[4][2*l]);
        float v1 = a_[0][2*l+1] + 0.25f*(a_[1][2*l+1]+a_[2][2*l+1]+a_[3][2*l+1]+a_[4][2*l+1]);
        vPu[l] = packh2(v0, v1);
        const int r = tid >> 1, h = tid & 1;
        const uint2* x2p = (const uint2*)vPu;
        float acc0 = h ? 0.f : b_agg[r], acc1 = 0.f;
        #pragma unroll
        for (int e2g = h*16; e2g < h*16+16; e2g += 2) {
          unsigned u00 = aggL[e2g*256 + r],     u01 = aggL[e2g*256 + 128 + r];
          uint2 x0 = x2p[e2g];
          acc0 = dot2(u00, x0.x, acc0); acc0 = dot2(u01, x0.y, acc0);
          unsigned u10 = aggL[(e2g+1)*256 + r], u11 = aggL[(e2g+1)*256 + 128 + r];
          uint2 x1 = x2p[e2g+1];
          acc1 = dot2(u10, x1.x, acc1); acc1 = dot2(u11, x1.y, acc1);
        }
        float acc = acc0 + acc1; acc += __shfl_xor(acc, 1);
        if (!h) ((_Float16*)m1Pu)[r] = (_Float16)ftanh(acc);
      } else if (tid < 432) {
        if (t >= 1) {
          const int g = (tid - 256) >> 4, lane = tid & 15;
          const int ne = (tp < RK ? tp : RK) + 1;
          if (g < ne) {
            const float* row;
            if (g == 0) row = g2fp[(t+1)&1];
            else {
              int s = (tp <= RK) ? (g-1) : idxk[tp][g-1];
              row = hist[s];
              if (lane == 0) kwv[g] = kwh[s];
            }
            const float* qp = qcs[tp & 1];
            float part = 0.f;
            #pragma unroll
            for (int k = 0; k < 8; ++k) { int d = lane + (k<<4); part += qp[d]*row[d]; }
            part += __shfl_xor(part, 8, 16);
            part += __shfl_xor(part, 4, 16);
            part += __shfl_xor(part, 2, 16);
            part += __shfl_xor(part, 1, 16);
            if (lane == 0) ogv[g] = part;
          }
        }
      } else if (tid < 512) {
        const int r = tid - 432;          // gh1 rows 0..79
        GH1_ROW(r);
      } else if (tid < 576) {
        if (t >= 1) {
          const int lane = tid & 63;
          float v = kevec[lane] + kevec[lane + 64];
          #pragma unroll
          for (int off = 32; off; off >>= 1) v += __shfl_down(v, off);
          if (lane == 0) { kwv[0] = v; if (tp >= 1) kwh[tp] = v; }
        }
      } else {
        const int r = 80 + (tid - 576);   // gh1 rows 80..271
        GH1_ROW(r);
      }
      __syncthreads();

      // ---- P4: ls -> xvPu (0-255) | y-write (256) | gh1 rows 272-383 (384-495) ----
      if (tid < 256) {
        const int r = tid >> 1, h = tid & 1;
        const unsigned* A = aggL + 16384;
        const uint2* x2p = (const uint2*)m1Pu;
        float acc0 = h ? 0.f : b_last[r], acc1 = 0.f;
        #pragma unroll
        for (int e2g = h*16; e2g < h*16+16; e2g += 2) {
          unsigned u00 = A[e2g*256 + r],     u01 = A[e2g*256 + 128 + r];
          uint2 x0 = x2p[e2g];
          acc0 = dot2(u00, x0.x, acc0); acc0 = dot2(u01, x0.y, acc0);
          unsigned u10 = A[(e2g+1)*256 + r], u11 = A[(e2g+1)*256 + 128 + r];
          uint2 x1 = x2p[e2g+1];
          acc1 = dot2(u10, x1.x, acc1); acc1 = dot2(u11, x1.y, acc1);
        }
        float acc = acc0 + acc1; acc += __shfl_xor(acc, 1);
        if (!h) ((_Float16*)xvPu)[r] = (_Float16)ftanh(acc);
      } else if (tid == 256) {
        if (t >= 1) {
          const int ne = (tp < RK ? tp : RK) + 1;
          float mx = kwv[0];
          for (int i2 = 1; i2 < ne; ++i2) mx = fmaxf(mx, kwv[i2]);
          float den = 0.f, num = 0.f;
          for (int i2 = 0; i2 < ne; ++i2) { float e_ = __expf(kwv[i2]-mx); den += e_; num += e_*ogv[i2]; }
          y[b*SS + ((tp==0) ? 0 : (tp+1))] = fsig(num/den);
        }
      } else if (tid >= 384 && tid < 496) {
        const int r = 272 + (tid - 384);  // gh1 rows 272..383
        GH1_ROW(r);
      }
      __syncthreads();

      // ---- P5: gi1 = ih1a . xv only (2thr/row, 96KB stream) ----
      {
        const uint4* xvp4 = (const uint4*)xvPu;
        float ai0 = hf ? 0.f : (b_ih1[r2] + gicorr[scc[t]][r2]), ai1 = 0.f;
        #pragma unroll
        for (int k = 0; k < 8; k += 2) {
          uint4 w0 = Wi1[k*768 + tid], w1 = Wi1[(k+1)*768 + tid];
          uint4 xa = xvp4[hf*8+k], xb = xvp4[hf*8+k+1];
          FD4(w0, xa, ai0); FD4(w1, xb, ai1);
        }
        float acc_i = ai0 + ai1; acc_i += __shfl_xor(acc_i, 1);
        if (!hf) gi1[r2] = acc_i;
      }
      __syncthreads();
    } else {
      // ---- P2'' (mask==0): og (256-431) | qry (512-767) | GRU1 both (all) ----
      if (tid >= 256 && tid < 432 && t >= 1) {
        const int g = (tid - 256) >> 4, lane = tid & 15;
        const int ne = (tp < RK ? tp : RK) + 1;
        if (g < ne) {
          const float* row;
          if (g == 0) row = g2fp[(t+1)&1];
          else {
            int s = (tp <= RK) ? (g-1) : idxk[tp][g-1];
            row = hist[s];
            if (lane == 0) kwv[g] = kwh[s];
          }
          const float* qp = qcs[tp & 1];
          float part = 0.f;
          #pragma unroll
          for (int k = 0; k < 8; ++k) { int d = lane + (k<<4); part += qp[d]*row[d]; }
          part += __shfl_xor(part, 8, 16);
          part += __shfl_xor(part, 4, 16);
          part += __shfl_xor(part, 2, 16);
          part += __shfl_xor(part, 1, 16);
          if (lane == 0) ogv[g] = part;
        }
      } else if (tid >= 512) {
        const int rq = (tid - 512) >> 1, hq = tid & 1;
        const uint4* g2p4 = (const uint4*)g2Pu;
        float a0 = hq ? 0.f : b_query[rq], a1 = 0.f;
        #pragma unroll
        for (int k = hq*8; k < hq*8+8; k += 2) {
          uint4 u0 = Wq4[k*128 + rq];     uint4 x0 = g2p4[k];   FD4(u0, x0, a0);
          uint4 u1 = Wq4[(k+1)*128 + rq]; uint4 x1 = g2p4[k+1]; FD4(u1, x1, a1);
        }
        float acc = a0 + a1; acc += __shfl_xor(acc, 1);
        if (!hq) kevec[rq] = ftanh(acc) * w_k[rq];
      }
      {
        const uint4* xvp4 = (const uint4*)xvPu;
        const uint4* h1p4 = (const uint4*)h1Pu;
        float ai0 = hf ? 0.f : (b_ih1[r2] + gicorr[scc[t]][r2]), ai1 = 0.f;
        float ah0 = hf ? 0.f : b_hh1[r2], ah1 = 0.f;
        #pragma unroll
        for (int k = 0; k < 8; k += 2) {
          uint4 w0 = Wi1[k*768 + tid], w1 = Wi1[(k+1)*768 + tid];
          uint4 xa = xvp4[hf*8+k], xb = xvp4[hf*8+k+1];
          FD4(w0, xa, ai0); FD4(w1, xb, ai1);
          uint4 v0 = Wh1[k*768 + tid], v1 = Wh1[(k+1)*768 + tid];
          uint4 ya = h1p4[hf*8+k], yb = h1p4[hf*8+k+1];
          FD4(v0, ya, ah0); FD4(v1, yb, ah1);
        }
        float acc_i = ai0 + ai1; acc_i += __shfl_xor(acc_i, 1);
        float acc_h = ah0 + ah1; acc_h += __shfl_xor(acc_h, 1);
        if (!hf) { gi1[r2] = acc_i; gh1[r2] = acc_h; }
      }
      __syncthreads();
    }

    // ---- P6: [mask==0: wave0 kw+y] ; redundant GRU1-nl ; GRU2 (pinned) ----
    if (!msk && t >= 1 && tid < 64) {
      float v = kevec[tid] + kevec[tid + 64];
      #pragma unroll
      for (int off = 32; off; off >>= 1) v += __shfl_down(v, off);
      if (tid == 0) {
        if (tp >= 1) kwh[tp] = v;
        const int ne = (tp < RK ? tp : RK) + 1;
        float mx = v;
        for (int i2 = 1; i2 < ne; ++i2) mx = fmaxf(mx, kwv[i2]);
        float den = __expf(v - mx), num = den*ogv[0];
        for (int i2 = 1; i2 < ne; ++i2) { float e_ = __expf(kwv[i2]-mx); den += e_; num += e_*ogv[i2]; }
        y[b*SS + ((tp==0) ? 0 : (tp+1))] = fsig(num/den);
      }
    }
    {
      const int l = tid & 63;
      float2 hold = ((const float2*)h1fp[(t+1)&1])[l];
      float2 hn = gru_nl2(((const float2*)gi1)[l], ((const float2*)(gi1+128))[l], ((const float2*)(gi1+256))[l],
                          ((const float2*)gh1)[l], ((const float2*)(gh1+128))[l], ((const float2*)(gh1+256))[l],
                          hold);
      ((float2*)h1fp[t&1])[l] = hn;
      h1Pu[l] = packh2(hn.x, hn.y);
    }
    {
      const uint4* xh1 = (const uint4*)h1Pu;
      const uint4* xh2 = (t <= 1) ? (const uint4*)h2iPu : (const uint4*)g2Pu;
      float ai0 = hf ? 0.f : b_ih2[r2], ai1 = 0.f;
      float ah0 = hf ? 0.f : b_hh2[r2], ah1 = 0.f;
      #pragma unroll
      for (int k = 0; k < 8; k += 2) {
        uint4 xa = xh1[hf*8+k], xb = xh1[hf*8+k+1];
        FD4(pwi[k], xa, ai0); FD4(pwi[k+1], xb, ai1);
        uint4 ya = xh2[hf*8+k], yb = xh2[hf*8+k+1];
        FD4(pwh[k], ya, ah0); FD4(pwh[k+1], yb, ah1);
      }
      float acc_i = ai0 + ai1; acc_i += __shfl_xor(acc_i, 1);
      float acc_h = ah0 + ah1; acc_h += __shfl_xor(acc_h, 1);
      if (!hf) { gi2[r2] = acc_i; gh2[r2] = acc_h; }
    }
    __syncthreads();
  }

  // ==== epilogue: finalize g2(62), predict(62) -> y[63] ====
  if (tid < 64) {
    const int l = tid;
    const float* ph2 = g2fp[1];
    float2 hold = ((const float2*)ph2)[l];
    float2 gv = gru_nl2(((const float2*)gi2)[l], ((const float2*)(gi2+128))[l], ((const float2*)(gi2+256))[l],
                        ((const float2*)gh2)[l], ((const float2*)(gh2+128))[l], ((const float2*)(gh2+256))[l],
                        hold);
    ((float2*)g2fp[0])[l] = gv;
    g2Pu[l] = packh2(gv.x, gv.y);
  }
  __syncthreads();
  if (tid < 128) {
    const int r = tid;
    const uint4* g2p4 = (const uint4*)g2Pu;
    float a0 = b_query[r], a1 = 0.f;
    #pragma unroll
    for (int k = 0; k < 16; k += 2) {
      uint4 u0 = Wq4[k*128 + r];     uint4 x0 = g2p4[k];   FD4(u0, x0, a0);
      uint4 u1 = Wq4[(k+1)*128 + r]; uint4 x1 = g2p4[k+1]; FD4(u1, x1, a1);
    }
    kevec[r] = ftanh(a0 + a1) * w_k[r];
  }
  __syncthreads();
  {
    const int tp = SS - 2;   // 62
    if (tid < 176) {
      const int g = tid >> 4, lane = tid & 15;
      const int ne = RK + 1;
      if (g < ne) {
        const float* row;
        if (g == 0) row = g2fp[0];
        else {
          int s = idxk[tp][g-1];
          row = hist[s];
          if (lane == 0) kwv[g] = kwh[s];
        }
        const float* qp = qcs[tp & 1];
        float part = 0.f;
        #pragma unroll
        for (int k = 0; k < 8; ++k) { int d = lane + (k<<4); part += qp[d]*row[d]; }
        part += __shfl_xor(part, 8, 16);
        part += __shfl_xor(part, 4, 16);
        part += __shfl_xor(part, 2, 16);
        part += __shfl_xor(part, 1, 16);
        if (lane == 0) ogv[g] = part;
      }
    } else if (tid >= 256 && tid < 320) {
      const int lane = tid & 63;
      float v = kevec[lane] + kevec[lane + 64];
      #pragma unroll
      for (int off = 32; off; off >>= 1) v += __shfl_down(v, off);
      if (lane == 0) kwv[0] = v;
    }
  }
  __syncthreads();
  if (tid == 0) {
    const int ne = RK + 1;
    float mx = kwv[0];
    for (int i2 = 1; i2 < ne; ++i2) mx = fmaxf(mx, kwv[i2]);
    float den = 0.f, num = 0.f;
    for (int i2 = 0; i2 < ne; ++i2) { float e_ = __expf(kwv[i2]-mx); den += e_; num += e_*ogv[i2]; }
    y[b*SS + SS - 1] = fsig(num/den);
  }
}

extern "C" void kernel_launch(void* const* d_in, const int* in_sizes, int n_in,
                              void* d_out, int out_size, void* d_ws, size_t ws_size,
                              hipStream_t stream)
{
  (void)in_sizes; (void)n_in; (void)out_size; (void)ws_size;

  const float* embQ  = (const float*)d_in[0];
  const float* embC  = (const float*)d_in[1];
  const float* embR  = (const float*)d_in[2];
  const float* Wih1  = (const float*)d_in[3];
  const float* Whh1  = (const float*)d_in[4];
  const float* bih1  = (const float*)d_in[5];
  const float* bhh1  = (const float*)d_in[6];
  const float* Wih2  = (const float*)d_in[7];
  const float* Whh2  = (const float*)d_in[8];
  const float* bih2  = (const float*)d_in[9];
  const float* bhh2  = (const float*)d_in[10];
  const float* Wagg  = (const float*)d_in[11];
  const float* bagg  = (const float*)d_in[12];
  const float* Wlast = (const float*)d_in[13];
  const float* blast = (const float*)d_in[14];
  const float* Wqry  = (const float*)d_in[15];
  const float* bqry  = (const float*)d_in[16];
  // d_in[17] W_key, [18] b_key, [19] w_q, [21] b_w cancel in the softmax -> unused
  const float* wk    = (const float*)d_in[20];
  const float* h1i   = (const float*)d_in[22];
  const float* h2i   = (const float*)d_in[23];
  const int* qnbr    = (const int*)d_in[24];
  const int* cnbr    = (const int*)d_in[25];
  const int* q2c     = (const int*)d_in[26];
  const int* qseq    = (const int*)d_in[27];
  const int* cseq    = (const int*)d_in[28];
  const int* mseq    = (const int*)d_in[29];

  unsigned* wsU = (unsigned*)d_ws;
  float* yout = (float*)d_out;

  gikt_pack<<<(TOTAL_U + 255) / 256, 256, 0, stream>>>(Wih1, Whh1, Wih2, Whh2, Wagg, Wlast, Wqry, wsU);
  gikt_main<<<BB, T, 0, stream>>>(embQ, embC, embR, bih1, bhh1, bih2, bhh2, bagg, blast, bqry,
                                  wk, h1i, h2i, qnbr, cnbr, q2c, qseq, cseq, mseq, wsU, yout);
}

// Round 12
// 573.163 us; speedup vs baseline: 1.3762x; 1.3762x over previous
//
#include <hip/hip_runtime.h>
#include <math.h>

#define D    128
#define QN   4
#define CN   4
#define MAXC 4
#define BB   128
#define SS   64
#define RK   10
#define T    768   // 12 waves

// ---- packed-fp16 weight workspace layout (uint32 units; each uint = 2 half) ----
#define UOFF_IH1A 0        // cols 0..127 of W_ih1, chunked NT=768 K=8 (streamed) -> 24576
#define UOFF_IH1B 24576    // cols 128..255 of W_ih1: [e2l][384] -> 24576
#define UOFF_HH1  49152    // chunked NT=768 K=8 (streamed) -> 24576
#define UOFF_IH2  73728    // chunked NT=768 K=8 (register-pinned, asm) -> 24576
#define UOFF_HH2  98304    // chunked NT=768 K=8 (register-pinned, asm) -> 24576
#define UOFF_QRY  122880   // [k][128] uint4, K=16 -> 8192
#define UOFF_A0   131072   // [e2g][2][128] -> 8192
#define UOFF_A1   139264   // -> 8192
#define UOFF_LS   147456   // -> 8192
#define TOTAL_U   155648

typedef _Float16 h2_t __attribute__((ext_vector_type(2)));
union U32H2 { unsigned u; h2_t h; unsigned short s2[2]; };

__device__ __forceinline__ unsigned h16f(float x){
  U32H2 c; c.h[0] = (_Float16)x; c.h[1] = (_Float16)0.f;
  return (unsigned)c.s2[0];
}
__device__ __forceinline__ unsigned packh2(float a, float b){
  U32H2 c; c.h[0] = (_Float16)a; c.h[1] = (_Float16)b;
  return c.u;
}
__device__ __forceinline__ float dot2(unsigned w, unsigned x, float acc){
  U32H2 a; a.u = w; U32H2 b; b.u = x;
  return __builtin_amdgcn_fdot2(a.h, b.h, acc, false);
}
__device__ __forceinline__ float hlo(unsigned u){ U32H2 a; a.u=u; return (float)a.h[0]; }
__device__ __forceinline__ float hhi(unsigned u){ U32H2 a; a.u=u; return (float)a.h[1]; }

__device__ __forceinline__ float fsig(float x){ return 1.f/(1.f + __expf(-x)); }
__device__ __forceinline__ float ftanh(float x){
  float xc = fminf(fmaxf(x, -30.f), 30.f);
  float e = __expf(2.f*xc);
  return (e - 1.f)/(e + 1.f);
}

#define FD4(w4, x4, acc) { \
  acc = dot2((w4).x, (x4).x, acc); acc = dot2((w4).y, (x4).y, acc); \
  acc = dot2((w4).z, (x4).z, acc); acc = dot2((w4).w, (x4).w, acc); }

// anti-rematerialization pin. HARD ENVELOPE: 64 pinned regs (GRU2 only).
// r8/r9/r10/r11 all proved the allocator caps at ~84 VGPRs and spills
// anything beyond (WRITE_SIZE 23.6K -> 37K/59K/73K).
#define KEEP4(v) asm volatile("" : "+v"((v).x), "+v"((v).y), "+v"((v).z), "+v"((v).w))

__global__ void gikt_pack(const float* __restrict__ Wih1,
                          const float* __restrict__ Whh1,
                          const float* __restrict__ Wih2,
                          const float* __restrict__ Whh2,
                          const float* __restrict__ Wagg,
                          const float* __restrict__ Wlast,
                          const float* __restrict__ Wqry,
                          unsigned* __restrict__ wsU)
{
  int i = blockIdx.x * blockDim.x + threadIdx.x;
  if (i >= TOTAL_U) return;
  const float* src = nullptr; int row = 0, e2 = 0, stride = 0;
  int j = i;
  if (j < 24576) {               // ih1a
    int c = j & 3, i4 = j >> 2, k = i4 / 768, t = i4 - k * 768, r = t >> 1, hf = t & 1;
    e2 = hf * 32 + k * 4 + c; row = r; src = Wih1; stride = 256;
  } else if ((j -= 24576) < 24576) {   // ih1b
    e2 = 64 + (j / 384); row = j % 384; src = Wih1; stride = 256;
  } else if ((j -= 24576) < 24576) {   // hh1
    int c = j & 3, i4 = j >> 2, k = i4 / 768, t = i4 - k * 768, r = t >> 1, hf = t & 1;
    e2 = hf * 32 + k * 4 + c; row = r; src = Whh1; stride = 128;
  } else if ((j -= 24576) < 24576) {   // ih2
    int c = j & 3, i4 = j >> 2, k = i4 / 768, t = i4 - k * 768, r = t >> 1, hf = t & 1;
    e2 = hf * 32 + k * 4 + c; row = r; src = Wih2; stride = 128;
  } else if ((j -= 24576) < 24576) {   // hh2
    int c = j & 3, i4 = j >> 2, k = i4 / 768, t = i4 - k * 768, r = t >> 1, hf = t & 1;
    e2 = hf * 32 + k * 4 + c; row = r; src = Whh2; stride = 128;
  } else if ((j -= 24576) < 8192) {    // qry
    int c = j & 3, i4 = j >> 2, k = i4 >> 7, r = i4 & 127;
    e2 = k * 4 + c; row = r; src = Wqry; stride = 128;
  } else if ((j -= 8192) < 8192) {     // a0
    int r = j & 127, p = (j >> 7) & 1, e2g = j >> 8;
    e2 = 2 * e2g + p; row = r; src = Wagg; stride = 128;
  } else if ((j -= 8192) < 8192) {     // a1
    int r = j & 127, p = (j >> 7) & 1, e2g = j >> 8;
    e2 = 2 * e2g + p; row = r; src = Wagg + 128 * 128; stride = 128;
  } else {                              // ls
    j -= 8192;
    int r = j & 127, p = (j >> 7) & 1, e2g = j >> 8;
    e2 = 2 * e2g + p; row = r; src = Wlast; stride = 128;
  }
  float lo = src[row * stride + 2 * e2];
  float hi = src[row * stride + 2 * e2 + 1];
  wsU[i] = h16f(lo) | (h16f(hi) << 16);
}

__device__ __forceinline__ float2 gru_nl2(float2 gr, float2 gz, float2 gn,
                                          float2 hr, float2 hz, float2 hn,
                                          float2 hold){
  float2 out;
  {
    float rg = fsig(gr.x + hr.x);
    float zg = fsig(gz.x + hz.x);
    float ng = ftanh(gn.x + rg*hn.x);
    out.x = (1.f-zg)*ng + zg*hold.x;
  }
  {
    float rg = fsig(gr.y + hr.y);
    float zg = fsig(gz.y + hz.y);
    float ng = ftanh(gn.y + rg*hn.y);
    out.y = (1.f-zg)*ng + zg*hold.y;
  }
  return out;
}

__launch_bounds__(T, 1)
__global__ void gikt_main(
    const float* __restrict__ embQ,
    const float* __restrict__ embC,
    const float* __restrict__ embR,
    const float* __restrict__ b_ih1,
    const float* __restrict__ b_hh1,
    const float* __restrict__ b_ih2,
    const float* __restrict__ b_hh2,
    const float* __restrict__ b_agg,
    const float* __restrict__ b_last,
    const float* __restrict__ b_query,
    const float* __restrict__ w_k,
    const float* __restrict__ h1i,
    const float* __restrict__ h2i,
    const int* __restrict__ qnbr,
    const int* __restrict__ cnbr,
    const int* __restrict__ q2c,
    const int* __restrict__ qseq,
    const int* __restrict__ cseq,
    const int* __restrict__ mseq,
    const unsigned* __restrict__ wsU,
    float* __restrict__ y)
{
  const int b   = blockIdx.x;
  const int tid = threadIdx.x;
  const int r2  = tid >> 1, hf = tid & 1;

  __shared__ unsigned aggL[3 * 8192];          // a0|a1|ls; phase0 alias: Gram
  __shared__ __align__(16) float hist[SS][132];// state history fp32 (row0 = zero)
  __shared__ float gicorr[2][384];
  __shared__ int   idxk[SS][RK];
  __shared__ float kwh[SS];
  __shared__ __align__(16) float a_[5][D];
  __shared__ __align__(16) float gi1[3*D];
  __shared__ __align__(16) float gh1[3*D];
  __shared__ __align__(16) float gi2[3*D];
  __shared__ __align__(16) float gh2[3*D];
  __shared__ __align__(16) float h1fp[2][D];
  __shared__ __align__(16) float g2fp[2][D];
  __shared__ __align__(16) float h2ifp[D];
  __shared__ __align__(16) float qcs[2][D];
  __shared__ float kevec[D];
  __shared__ __align__(16) unsigned mPu[5][64];
  __shared__ __align__(16) unsigned vPu[64];
  __shared__ __align__(16) unsigned m1Pu[64];
  __shared__ __align__(16) unsigned xvPu[64];
  __shared__ __align__(16) unsigned h1Pu[64];
  __shared__ __align__(16) unsigned g2Pu[64];
  __shared__ __align__(16) unsigned h2iPu[64];
  __shared__ int   sq[SS], scc[SS], smk[SS];
  __shared__ int   nn1[SS][QN], nn2[SS][QN*CN], cc2[SS][MAXC];
  __shared__ float red[12];
  __shared__ float ogv[16], kwv[16];

  float (*G)[65] = (float(*)[65])aggL;

  // ---- pinned GRU2 weights: 16 uint4 = 64 VGPR, pinned via asm ----
  uint4 pwi[8], pwh[8];
  {
    const uint4* Pi = (const uint4*)(wsU + UOFF_IH2);
    const uint4* Ph = (const uint4*)(wsU + UOFF_HH2);
    #pragma unroll
    for (int k = 0; k < 8; ++k) { pwi[k] = Pi[k*768 + tid]; pwh[k] = Ph[k*768 + tid]; }
    #pragma unroll
    for (int k = 0; k < 8; ++k) { KEEP4(pwi[k]); KEEP4(pwh[k]); }
  }

  // ---- phase 0a: sequences ----
  for (int i = tid; i < SS; i += T) { sq[i]=qseq[b*SS+i]; scc[i]=cseq[b*SS+i]; smk[i]=mseq[b*SS+i]; }
  __syncthreads();

  // ---- phase 0b: E rows into hist; 1-hop indices ----
  for (int i = tid; i < SS*32; i += T) {
    int s = i >> 5, e4 = i & 31;
    float4 v = ((const float4*)(embQ + sq[s]*D))[e4];
    ((float4*)hist[s])[e4] = v;
  }
  for (int i = tid; i < (SS-1)*QN; i += T)   { int t = i>>2, j = i&3; nn1[t][j] = qnbr[sq[t]*QN + j]; }
  for (int i = tid; i < (SS-1)*MAXC; i += T) { int t = i>>2, j = i&3; cc2[t][j] = q2c[sq[t+1]*MAXC + j]; }
  __syncthreads();

  // ---- phase 0c: Gram (fp32, float4), 2-hop indices, gicorr ----
  for (int p = tid; p < SS*SS; p += T) {
    int tq = p >> 6, s = p & 63;
    if (tq >= RK+2 && s < tq-1) {
      const float4* ra = (const float4*)hist[tq];
      const float4* rb = (const float4*)hist[s];
      float acc = 0.f;
      #pragma unroll 8
      for (int d4 = 0; d4 < 32; ++d4) {
        float4 xa = ra[d4], xb = rb[d4];
        acc += xa.x*xb.x + xa.y*xb.y + xa.z*xb.z + xa.w*xb.w;
      }
      G[tq-(RK+2)][s] = acc;
    }
  }
  for (int i = tid; i < (SS-1)*QN*CN; i += T) {
    int t = i>>4, j = (i>>2)&3, l = i&3;
    nn2[t][j*CN+l] = cnbr[nn1[t][j]*CN + l];
  }
  {
    const int c = (tid >= 384) ? 1 : 0, r = tid - (c ? 384 : 0);
    const float2* er2 = (const float2*)(embR + c*D);
    float acc = 0.f;
    #pragma unroll 4
    for (int e2l = 0; e2l < 64; ++e2l) {
      unsigned u = wsU[UOFF_IH1B + e2l*384 + r];
      float2 x = er2[e2l];
      acc += hlo(u)*x.x + hhi(u)*x.y;
    }
    gicorr[c][r] = acc;
  }
  __syncthreads();

  // ---- phase 0d: stable top-k (ties -> lowest index, = jax.lax.top_k) ----
  if (tid < 52) {
    int t = RK + 1 + tid;
    for (int k = 0; k < RK; ++k) {
      float best = -INFINITY; int bi = 0;
      for (int s = 0; s < t; ++s) { float v = G[tid][s]; if (v > best) { best = v; bi = s; } }
      idxk[t][k] = bi;
      G[tid][bi] = -INFINITY;
    }
  }
  __syncthreads();

  // ---- phase 0e: agg weights into LDS; state init; kw(zero-state) ----
  for (int i = tid; i < 3*8192; i += T) aggL[i] = wsU[UOFF_A0 + i];
  if (tid < 64) {
    float a0 = h1i[b*D+2*tid], a1 = h1i[b*D+2*tid+1];
    h1Pu[tid] = packh2(a0, a1);
    ((float2*)h1fp[1])[tid] = make_float2(a0, a1);
    float c0 = h2i[b*D+2*tid], c1 = h2i[b*D+2*tid+1];
    h2iPu[tid] = packh2(c0, c1);
    ((float2*)h2ifp)[tid] = make_float2(c0, c1);
    g2Pu[tid] = 0;
  }
  if (tid < D) hist[0][tid] = 0.f;
  if (tid == 0) y[b*SS + 1] = 0.f;   // never written by reference
  {
    float p0 = (tid < D) ? w_k[tid]*ftanh(b_query[tid]) : 0.f;
    #pragma unroll
    for (int off = 32; off; off >>= 1) p0 += __shfl_down(p0, off);
    if ((tid & 63) == 0) red[tid >> 6] = p0;
  }
  __syncthreads();
  if (tid == 0) kwh[0] = red[0]+red[1];
  __syncthreads();

  const uint4* Wi1 = (const uint4*)(wsU + UOFF_IH1A);
  const uint4* Wh1 = (const uint4*)(wsU + UOFF_HH1);
  const uint4* Wq4 = (const uint4*)(wsU + UOFF_QRY);

  // ---- cross-step gather prefetch registers ----
  float pf0 = 0.f, pf1 = 0.f, pf2 = 0.f, pf3 = 0.f, pf4 = 0.f;

#define PREFETCH(tt) {                                                        \
    const int d_ = tid & 127, grp_ = tid >> 7;                                \
    const bool m2_ = (smk[tt] != 0);                                          \
    if (grp_ == 0) {                                                          \
      pf0 = embQ[sq[tt]*D + d_];                                              \
      if (m2_) { pf1 = embC[nn1[tt][0]*D+d_]; pf2 = embC[nn1[tt][1]*D+d_];    \
                 pf3 = embC[nn1[tt][2]*D+d_]; pf4 = embC[nn1[tt][3]*D+d_]; }  \
    } else if (grp_ <= 4) {                                                   \
      if (m2_) { const int j_ = grp_ - 1;                                     \
        pf0 = embC[nn1[tt][j_]*D + d_];                                       \
        pf1 = embQ[nn2[tt][j_*CN+0]*D+d_]; pf2 = embQ[nn2[tt][j_*CN+1]*D+d_]; \
        pf3 = embQ[nn2[tt][j_*CN+2]*D+d_]; pf4 = embQ[nn2[tt][j_*CN+3]*D+d_];}\
    } else {                                                                  \
      pf0 = embQ[sq[(tt)+1]*D + d_];                                          \
      pf1 = embC[cc2[tt][0]*D+d_]; pf2 = embC[cc2[tt][1]*D+d_];               \
      pf3 = embC[cc2[tt][2]*D+d_]; pf4 = embC[cc2[tt][3]*D+d_];               \
    } }

  PREFETCH(0);

  // ==== time loop: step t runs GRU(t); g2(t-1) finalizes in P1; predict(t-1) overlapped ====
  for (int t = 0; t < SS-1; ++t) {
    const int tp = t - 1;
    const bool msk = (smk[t] != 0);

    // ---- P1: wave0 finalizes g2(t-1); consume prefetch; issue prefetch(t+1) ----
    if (tid < 64 && t >= 1) {
      const int l = tid;
      const float* ph2 = (t <= 2) ? h2ifp : g2fp[t & 1];
      float2 hold = ((const float2*)ph2)[l];
      float2 gv = gru_nl2(((const float2*)gi2)[l], ((const float2*)(gi2+128))[l], ((const float2*)(gi2+256))[l],
                          ((const float2*)gh2)[l], ((const float2*)(gh2+128))[l], ((const float2*)(gh2+256))[l],
                          hold);
      ((float2*)g2fp[(t+1)&1])[l] = gv;
      g2Pu[l] = packh2(gv.x, gv.y);
      if (t >= 2) { hist[t-1][2*l] = gv.x; hist[t-1][2*l+1] = gv.y; }
    }
    {
      const int d = tid & 127, grp = tid >> 7;
      if (msk) {
        if (grp <= 4) ((_Float16*)mPu[grp])[d] = (_Float16)(pf0 + 0.25f*(pf1+pf2+pf3+pf4));
        else          qcs[t & 1][d] = pf0+pf1+pf2+pf3+pf4;
      } else {
        if (grp == 0)      ((_Float16*)xvPu)[d] = (_Float16)pf0;
        else if (grp == 5) qcs[t & 1][d] = pf0+pf1+pf2+pf3+pf4;
      }
    }
    if (t + 1 < SS-1) PREFETCH(t+1);
    __syncthreads();

    if (msk) {
      // ---- P2: agg1 (0..639) | qry on g2(t-1) (640..767, 1 thread/row) ----
      if (tid < 640) {
        const int which = tid >> 7, r = tid & 127;
        const unsigned* A = aggL + (which ? 8192 : 0);
        const uint2* x2p = (const uint2*)mPu[which];
        float acc = (which == 0) ? b_agg[r] : b_agg[D + r];
        #pragma unroll 8
        for (int e2g = 0; e2g < 32; ++e2g) {
          unsigned u0 = A[e2g*256 + r];
          unsigned u1 = A[e2g*256 + 128 + r];
          uint2 xu = x2p[e2g];
          acc = dot2(u0, xu.x, acc);
          acc = dot2(u1, xu.y, acc);
        }
        a_[which][r] = ftanh(acc);
      } else {
        const int r = tid - 640;
        const uint4* g2p4 = (const uint4*)g2Pu;
        float acc = b_query[r];
        #pragma unroll
        for (int k = 0; k < 16; ++k) {
          uint4 u = Wq4[k*128 + r];
          uint4 xu = g2p4[k];
          FD4(u, xu, acc);
        }
        kevec[r] = ftanh(acc) * w_k[r];
      }
      __syncthreads();

      // ---- P3: agg2 (0..255) | og-prev (256..431) | kw-reduce (512..575) ----
      if (tid < 256) {
        const int l = tid & 63;
        float v0 = a_[0][2*l]   + 0.25f*(a_[1][2*l]  +a_[2][2*l]  +a_[3][2*l]  +a_[4][2*l]);
        float v1 = a_[0][2*l+1] + 0.25f*(a_[1][2*l+1]+a_[2][2*l+1]+a_[3][2*l+1]+a_[4][2*l+1]);
        vPu[l] = packh2(v0, v1);
        const int r = tid >> 1, h = tid & 1;
        const uint2* x2p = (const uint2*)vPu;
        float acc = h ? 0.f : b_agg[r];
        #pragma unroll
        for (int e2g = h*16; e2g < h*16+16; ++e2g) {
          unsigned u0 = aggL[e2g*256 + r];
          unsigned u1 = aggL[e2g*256 + 128 + r];
          uint2 xu = x2p[e2g];
          acc = dot2(u0, xu.x, acc);
          acc = dot2(u1, xu.y, acc);
        }
        acc += __shfl_xor(acc, 1);
        if (!h) ((_Float16*)m1Pu)[r] = (_Float16)ftanh(acc);
      } else if (tid >= 256 && tid < 432 && t >= 1) {
        const int g = (tid - 256) >> 4, lane = tid & 15;
        const int ne = (tp < RK ? tp : RK) + 1;
        if (g < ne) {
          const float* row;
          if (g == 0) row = g2fp[(t+1)&1];        // g2(t-1)
          else {
            int s = (tp <= RK) ? (g-1) : idxk[tp][g-1];
            row = hist[s];
            if (lane == 0) kwv[g] = kwh[s];
          }
          const float* qp = qcs[tp & 1];
          float part = 0.f;
          #pragma unroll
          for (int k = 0; k < 8; ++k) { int d = lane + (k<<4); part += qp[d]*row[d]; }
          part += __shfl_xor(part, 8, 16);
          part += __shfl_xor(part, 4, 16);
          part += __shfl_xor(part, 2, 16);
          part += __shfl_xor(part, 1, 16);
          if (lane == 0) ogv[g] = part;
        }
      } else if (tid >= 512 && tid < 576 && t >= 1) {
        const int lane = tid & 63;
        float v = kevec[lane] + kevec[lane + 64];
        #pragma unroll
        for (int off = 32; off; off >>= 1) v += __shfl_down(v, off);
        if (lane == 0) { kwv[0] = v; if (tp >= 1) kwh[tp] = v; }
      }
      __syncthreads();

      // ---- P4: ls -> xv packed (0..255) | y-write prev (tid 256) ----
      if (tid < 256) {
        const int r = tid >> 1, h = tid & 1;
        const unsigned* A = aggL + 16384;
        const uint2* x2p = (const uint2*)m1Pu;
        float acc = h ? 0.f : b_last[r];
        #pragma unroll
        for (int e2g = h*16; e2g < h*16+16; ++e2g) {
          unsigned u0 = A[e2g*256 + r];
          unsigned u1 = A[e2g*256 + 128 + r];
          uint2 xu = x2p[e2g];
          acc = dot2(u0, xu.x, acc);
          acc = dot2(u1, xu.y, acc);
        }
        acc += __shfl_xor(acc, 1);
        if (!h) ((_Float16*)xvPu)[r] = (_Float16)ftanh(acc);
      } else if (tid == 256 && t >= 1) {
        const int ne = (tp < RK ? tp : RK) + 1;
        float mx = kwv[0];
        for (int i2 = 1; i2 < ne; ++i2) mx = fmaxf(mx, kwv[i2]);
        float den = 0.f, num = 0.f;
        for (int i2 = 0; i2 < ne; ++i2) { float e_ = __expf(kwv[i2]-mx); den += e_; num += e_*ogv[i2]; }
        y[b*SS + ((tp==0) ? 0 : (tp+1))] = fsig(num/den);
      }
      __syncthreads();

      // ---- P5: GRU1 matvecs (768, 2thr/row, streamed weights) ----
      {
        const uint4* xvp4 = (const uint4*)xvPu;
        const uint4* h1p4 = (const uint4*)h1Pu;
        float acc_i = hf ? 0.f : (b_ih1[r2] + gicorr[scc[t]][r2]);
        float acc_h = hf ? 0.f : b_hh1[r2];
        #pragma unroll
        for (int k = 0; k < 8; ++k) {
          uint4 u = Wi1[k*768 + tid];
          uint4 xu = xvp4[hf*8 + k];
          FD4(u, xu, acc_i);
        }
        #pragma unroll
        for (int k = 0; k < 8; ++k) {
          uint4 u = Wh1[k*768 + tid];
          uint4 xu = h1p4[hf*8 + k];
          FD4(u, xu, acc_h);
        }
        acc_i += __shfl_xor(acc_i, 1);
        acc_h += __shfl_xor(acc_h, 1);
        if (!hf) { gi1[r2] = acc_i; gh1[r2] = acc_h; }
      }
      __syncthreads();
    } else {
      // ---- P2'' (mask==0): og + qry pre-work, then GRU1 on all threads ----
      if (tid >= 256 && tid < 432 && t >= 1) {
        const int g = (tid - 256) >> 4, lane = tid & 15;
        const int ne = (tp < RK ? tp : RK) + 1;
        if (g < ne) {
          const float* row;
          if (g == 0) row = g2fp[(t+1)&1];
          else {
            int s = (tp <= RK) ? (g-1) : idxk[tp][g-1];
            row = hist[s];
            if (lane == 0) kwv[g] = kwh[s];
          }
          const float* qp = qcs[tp & 1];
          float part = 0.f;
          #pragma unroll
          for (int k = 0; k < 8; ++k) { int d = lane + (k<<4); part += qp[d]*row[d]; }
          part += __shfl_xor(part, 8, 16);
          part += __shfl_xor(part, 4, 16);
          part += __shfl_xor(part, 2, 16);
          part += __shfl_xor(part, 1, 16);
          if (lane == 0) ogv[g] = part;
        }
      } else if (tid >= 512) {
        const int rq = (tid - 512) >> 1, hq = tid & 1;
        const uint4* g2p4 = (const uint4*)g2Pu;
        float a0 = hq ? 0.f : b_query[rq], a1 = 0.f;
        #pragma unroll
        for (int k = hq*8; k < hq*8+8; k += 2) {
          uint4 u0 = Wq4[k*128 + rq];     uint4 x0 = g2p4[k];   FD4(u0, x0, a0);
          uint4 u1 = Wq4[(k+1)*128 + rq]; uint4 x1 = g2p4[k+1]; FD4(u1, x1, a1);
        }
        float acc = a0 + a1; acc += __shfl_xor(acc, 1);
        if (!hq) kevec[rq] = ftanh(acc) * w_k[rq];
      }
      {
        const uint4* xvp4 = (const uint4*)xvPu;
        const uint4* h1p4 = (const uint4*)h1Pu;
        float ai0 = hf ? 0.f : (b_ih1[r2] + gicorr[scc[t]][r2]), ai1 = 0.f;
        float ah0 = hf ? 0.f : b_hh1[r2], ah1 = 0.f;
        #pragma unroll
        for (int k = 0; k < 8; k += 2) {
          uint4 w0 = Wi1[k*768 + tid], w1 = Wi1[(k+1)*768 + tid];
          uint4 xa = xvp4[hf*8+k], xb = xvp4[hf*8+k+1];
          FD4(w0, xa, ai0); FD4(w1, xb, ai1);
          uint4 v0 = Wh1[k*768 + tid], v1 = Wh1[(k+1)*768 + tid];
          uint4 ya = h1p4[hf*8+k], yb = h1p4[hf*8+k+1];
          FD4(v0, ya, ah0); FD4(v1, yb, ah1);
        }
        float acc_i = ai0 + ai1; acc_i += __shfl_xor(acc_i, 1);
        float acc_h = ah0 + ah1; acc_h += __shfl_xor(acc_h, 1);
        if (!hf) { gi1[r2] = acc_i; gh1[r2] = acc_h; }
      }
      __syncthreads();
    }

    // ---- P6: [mask==0: wave0 kw+y] ; redundant GRU1-nl ; GRU2 (pinned) ----
    if (!msk && t >= 1 && tid < 64) {
      float v = kevec[tid] + kevec[tid + 64];
      #pragma unroll
      for (int off = 32; off; off >>= 1) v += __shfl_down(v, off);
      if (tid == 0) {
        if (tp >= 1) kwh[tp] = v;
        const int ne = (tp < RK ? tp : RK) + 1;
        float mx = v;
        for (int i2 = 1; i2 < ne; ++i2) mx = fmaxf(mx, kwv[i2]);
        float den = __expf(v - mx), num = den*ogv[0];
        for (int i2 = 1; i2 < ne; ++i2) { float e_ = __expf(kwv[i2]-mx); den += e_; num += e_*ogv[i2]; }
        y[b*SS + ((tp==0) ? 0 : (tp+1))] = fsig(num/den);
      }
    }
    {
      const int l = tid & 63;
      float2 hold = ((const float2*)h1fp[(t+1)&1])[l];
      float2 hn = gru_nl2(((const float2*)gi1)[l], ((const float2*)(gi1+128))[l], ((const float2*)(gi1+256))[l],
                          ((const float2*)gh1)[l], ((const float2*)(gh1+128))[l], ((const float2*)(gh1+256))[l],
                          hold);
      ((float2*)h1fp[t&1])[l] = hn;
      h1Pu[l] = packh2(hn.x, hn.y);
    }
    {
      const uint4* xh1 = (const uint4*)h1Pu;
      const uint4* xh2 = (t <= 1) ? (const uint4*)h2iPu : (const uint4*)g2Pu;
      float acc_i = hf ? 0.f : b_ih2[r2];
      float acc_h = hf ? 0.f : b_hh2[r2];
      #pragma unroll
      for (int k = 0; k < 8; ++k) {
        uint4 xi = xh1[hf*8 + k];
        FD4(pwi[k], xi, acc_i);
        uint4 xx = xh2[hf*8 + k];
        FD4(pwh[k], xx, acc_h);
      }
      acc_i += __shfl_xor(acc_i, 1);
      acc_h += __shfl_xor(acc_h, 1);
      if (!hf) { gi2[r2] = acc_i; gh2[r2] = acc_h; }
    }
    __syncthreads();
  }

  // ==== epilogue: finalize g2(62), predict(62) -> y[63] ====
  if (tid < 64) {
    const int l = tid;
    const float* ph2 = g2fp[1];
    float2 hold = ((const float2*)ph2)[l];
    float2 gv = gru_nl2(((const float2*)gi2)[l], ((const float2*)(gi2+128))[l], ((const float2*)(gi2+256))[l],
                        ((const float2*)gh2)[l], ((const float2*)(gh2+128))[l], ((const float2*)(gh2+256))[l],
                        hold);
    ((float2*)g2fp[0])[l] = gv;
    g2Pu[l] = packh2(gv.x, gv.y);
  }
  __syncthreads();
  if (tid < 128) {
    const int r = tid;
    const uint4* g2p4 = (const uint4*)g2Pu;
    float a0 = b_query[r], a1 = 0.f;
    #pragma unroll
    for (int k = 0; k < 16; k += 2) {
      uint4 u0 = Wq4[k*128 + r];     uint4 x0 = g2p4[k];   FD4(u0, x0, a0);
      uint4 u1 = Wq4[(k+1)*128 + r]; uint4 x1 = g2p4[k+1]; FD4(u1, x1, a1);
    }
    kevec[r] = ftanh(a0 + a1) * w_k[r];
  }
  __syncthreads();
  {
    const int tp = SS - 2;   // 62
    if (tid < 176) {
      const int g = tid >> 4, lane = tid & 15;
      const int ne = RK + 1;
      if (g < ne) {
        const float* row;
        if (g == 0) row = g2fp[0];
        else {
          int s = idxk[tp][g-1];
          row = hist[s];
          if (lane == 0) kwv[g] = kwh[s];
        }
        const float* qp = qcs[tp & 1];
        float part = 0.f;
        #pragma unroll
        for (int k = 0; k < 8; ++k) { int d = lane + (k<<4); part += qp[d]*row[d]; }
        part += __shfl_xor(part, 8, 16);
        part += __shfl_xor(part, 4, 16);
        part += __shfl_xor(part, 2, 16);
        part += __shfl_xor(part, 1, 16);
        if (lane == 0) ogv[g] = part;
      }
    } else if (tid >= 256 && tid < 320) {
      const int lane = tid & 63;
      float v = kevec[lane] + kevec[lane + 64];
      #pragma unroll
      for (int off = 32; off; off >>= 1) v += __shfl_down(v, off);
      if (lane == 0) kwv[0] = v;
    }
  }
  __syncthreads();
  if (tid == 0) {
    const int ne = RK + 1;
    float mx = kwv[0];
    for (int i2 = 1; i2 < ne; ++i2) mx = fmaxf(mx, kwv[i2]);
    float den = 0.f, num = 0.f;
    for (int i2 = 0; i2 < ne; ++i2) { float e_ = __expf(kwv[i2]-mx); den += e_; num += e_*ogv[i2]; }
    y[b*SS + SS - 1] = fsig(num/den);
  }
}

extern "C" void kernel_launch(void* const* d_in, const int* in_sizes, int n_in,
                              void* d_out, int out_size, void* d_ws, size_t ws_size,
                              hipStream_t stream)
{
  (void)in_sizes; (void)n_in; (void)out_size; (void)ws_size;

  const float* embQ  = (const float*)d_in[0];
  const float* embC  = (const float*)d_in[1];
  const float* embR  = (const float*)d_in[2];
  const float* Wih1  = (const float*)d_in[3];
  const float* Whh1  = (const float*)d_in[4];
  const float* bih1  = (const float*)d_in[5];
  const float* bhh1  = (const float*)d_in[6];
  const float* Wih2  = (const float*)d_in[7];
  const float* Whh2  = (const float*)d_in[8];
  const float* bih2  = (const float*)d_in[9];
  const float* bhh2  = (const float*)d_in[10];
  const float* Wagg  = (const float*)d_in[11];
  const float* bagg  = (const float*)d_in[12];
  const float* Wlast = (const float*)d_in[13];
  const float* blast = (const float*)d_in[14];
  const float* Wqry  = (const float*)d_in[15];
  const float* bqry  = (const float*)d_in[16];
  // d_in[17] W_key, [18] b_key, [19] w_q, [21] b_w cancel in the softmax -> unused
  const float* wk    = (const float*)d_in[20];
  const float* h1i   = (const float*)d_in[22];
  const float* h2i   = (const float*)d_in[23];
  const int* qnbr    = (const int*)d_in[24];
  const int* cnbr    = (const int*)d_in[25];
  const int* q2c     = (const int*)d_in[26];
  const int* qseq    = (const int*)d_in[27];
  const int* cseq    = (const int*)d_in[28];
  const int* mseq    = (const int*)d_in[29];

  unsigned* wsU = (unsigned*)d_ws;
  float* yout = (float*)d_out;

  gikt_pack<<<(TOTAL_U + 255) / 256, 256, 0, stream>>>(Wih1, Whh1, Wih2, Whh2, Wagg, Wlast, Wqry, wsU);
  gikt_main<<<BB, T, 0, stream>>>(embQ, embC, embR, bih1, bhh1, bih2, bhh2, bagg, blast, bqry,
                                  wk, h1i, h2i, qnbr, cnbr, q2c, qseq, cseq, mseq, wsU, yout);
}